// Round 1
// baseline (142.428 us; speedup 1.0000x reference)
//
#include <hip/hip_runtime.h>
#include <stdint.h>

// TopKLayer (quirky sparse_hw): per row of 3136 elems, keep the t smallest-|x|
// elements where t = spatial index of the k-th largest |x| (k=313), with
// JAX-stable tie semantics. One block per row, radix-select on abs bits.

#define HW 3136
#define NT 256
#define K_SEL 313
#define CHUNK 13  // 256*13 = 3328 >= 3136

__device__ __forceinline__ unsigned block_scan_incl(unsigned v, unsigned* wt) {
    const int lane = threadIdx.x & 63;
    const int w = threadIdx.x >> 6;
    // intra-wave inclusive scan (wave64)
    for (int d = 1; d < 64; d <<= 1) {
        unsigned o = __shfl_up(v, d, 64);
        if (lane >= d) v += o;
    }
    if (lane == 63) wt[w] = v;
    __syncthreads();
    unsigned add = 0;
    for (int i = 0; i < w; ++i) add += wt[i];
    __syncthreads();  // wt safe for reuse after this
    return v + add;
}

// Radix select over keys key[j] = s_x[j] & 0x7fffffff.
// fromTop: find the rank-th largest (rank is 1-based); else rank-th smallest.
// Returns: V (exact 31-bit key), outside (# strictly greater if fromTop, else
// # strictly less), m (1-based occurrence target among elements == V).
__device__ void radix_select(const unsigned* s_x, unsigned* s_hist,
                             unsigned* s_scanws, unsigned* s_bcast,
                             unsigned rank, bool fromTop,
                             unsigned& Vout, unsigned& outsideOut, unsigned& mOut) {
    unsigned prefix = 0, pmask = 0;
    unsigned m = rank;
    unsigned outside = 0;
    const int shifts[4] = {23, 15, 7, 0};
    const unsigned bmasks[4] = {255u, 255u, 255u, 127u};
#pragma unroll
    for (int p = 0; p < 4; ++p) {
        const int shift = shifts[p];
        const unsigned bmask = bmasks[p];
        const int nb = (int)bmask + 1;
        for (int i = threadIdx.x; i < nb; i += NT) s_hist[i] = 0;
        __syncthreads();
        for (int j = threadIdx.x; j < HW; j += NT) {
            unsigned key = s_x[j] & 0x7fffffffu;
            if ((key & pmask) == prefix)
                atomicAdd(&s_hist[(key >> shift) & bmask], 1u);
        }
        __syncthreads();
        // locate the bin containing rank m (scanning from top or bottom)
        const int t = threadIdx.x;
        unsigned g = 0;
        if (t < nb) g = fromTop ? s_hist[bmask - (unsigned)t] : s_hist[t];
        unsigned S = block_scan_incl(g, s_scanws);
        if (t < nb && S >= m && (S - g) < m) {
            unsigned b = fromTop ? (bmask - (unsigned)t) : (unsigned)t;
            s_bcast[0] = b;
            s_bcast[1] = S - g;  // count outside (beyond) this bin so far
        }
        __syncthreads();
        unsigned b = s_bcast[0];
        unsigned add = s_bcast[1];
        __syncthreads();
        prefix |= b << shift;
        pmask |= bmask << shift;
        m -= add;
        outside += add;
    }
    Vout = prefix;
    outsideOut = outside;
    mOut = m;
}

// Index of the m-th (1-based, by increasing index) element with key == V.
__device__ unsigned find_mth_equal(const unsigned* s_x, unsigned* s_scanws,
                                   unsigned* s_bcast, unsigned V, unsigned m) {
    const int t = threadIdx.x;
    const int beg = t * CHUNK;
    const int end = min(beg + CHUNK, HW);
    unsigned c = 0;
    for (int j = beg; j < end; ++j)
        if ((s_x[j] & 0x7fffffffu) == V) c++;
    unsigned S = block_scan_incl(c, s_scanws);
    unsigned pre = S - c;
    if (c > 0 && pre < m && m <= S) {
        unsigned need = m - pre;
        for (int j = beg; j < end; ++j) {
            if ((s_x[j] & 0x7fffffffu) == V) {
                if (--need == 0) { s_bcast[2] = (unsigned)j; break; }
            }
        }
    }
    __syncthreads();
    unsigned r = s_bcast[2];
    __syncthreads();
    return r;
}

extern "C" __global__ void __launch_bounds__(NT)
topk_kernel(const float* __restrict__ x, float* __restrict__ out) {
    __shared__ uint4 s_x4[HW / 4];
    __shared__ unsigned s_hist[256];
    __shared__ unsigned s_scanws[4];
    __shared__ unsigned s_bcast[4];
    unsigned* s_x = (unsigned*)s_x4;

    const int row = blockIdx.x;
    const float4* __restrict__ xin = (const float4*)(x + (size_t)row * HW);
    float4* __restrict__ xout = (float4*)(out + (size_t)row * HW);

    for (int j = threadIdx.x; j < HW / 4; j += NT) {
        float4 v = xin[j];
        s_x4[j] = *(uint4*)&v;  // raw bits
    }
    __syncthreads();

    // Select A: value + stable index of the k-th largest |x|
    unsigned V, greater, mA;
    radix_select(s_x, s_hist, s_scanws, s_bcast, K_SEL, true, V, greater, mA);
    unsigned tIdx = find_mth_equal(s_x, s_scanws, s_bcast, V, mA);

    if (tIdx == 0) {  // keep nothing
        float4 z = make_float4(0.f, 0.f, 0.f, 0.f);
        for (int j = threadIdx.x; j < HW / 4; j += NT) xout[j] = z;
        return;
    }

    // Select B: keep the tIdx smallest (stable)
    unsigned W, less, keepEq;
    radix_select(s_x, s_hist, s_scanws, s_bcast, tIdx, false, W, less, keepEq);
    // keepEq = tIdx - less = number of elements equal to W to keep (by index order)

    {
        const int t = threadIdx.x;
        const int beg = t * CHUNK;
        const int end = min(beg + CHUNK, HW);
        unsigned c = 0;
        for (int j = beg; j < end; ++j)
            if ((s_x[j] & 0x7fffffffu) == W) c++;
        unsigned S = block_scan_incl(c, s_scanws);
        unsigned occ = S - c;  // occurrences of W before my chunk
        for (int j = beg; j < end; ++j) {
            unsigned key = s_x[j] & 0x7fffffffu;
            bool keep;
            if (key < W) keep = true;
            else if (key == W) { keep = (occ < keepEq); occ++; }
            else keep = false;
            if (!keep) s_x[j] = 0u;  // 0.0f bits
        }
    }
    __syncthreads();

    for (int j = threadIdx.x; j < HW / 4; j += NT)
        xout[j] = *(float4*)&s_x4[j];
}

extern "C" void kernel_launch(void* const* d_in, const int* in_sizes, int n_in,
                              void* d_out, int out_size, void* d_ws, size_t ws_size,
                              hipStream_t stream) {
    const float* x = (const float*)d_in[0];
    float* out = (float*)d_out;
    const int rows = in_sizes[0] / HW;  // 32*256 = 8192
    topk_kernel<<<dim3(rows), dim3(NT), 0, stream>>>(x, out);
}

// Round 2
// 106.029 us; speedup vs baseline: 1.3433x; 1.3433x over previous
//
#include <hip/hip_runtime.h>
#include <stdint.h>

// TopKLayer quirky sparse_hw: per row (3136 elems), t = spatial index of the
// k-th largest |x| (k=313, ties by ascending index); keep the t smallest-|x|
// elements (stable). One block per row. Single 2048-bin histogram drives both
// order-statistic selections; refinement runs on a compacted candidate bin.

#define HW   3136
#define NT   256
#define KSEL 313u
#define NB0  2048        // top 11 bits of 31-bit abs key
#define SP0  (NB0 / NT)  // 8
#define NB1  1024        // 10-bit refinement digits
#define SP1  (NB1 / NT)  // 4
#define CAP  512         // candidate capacity (stat max ~245 for N(0,1) rows)

__device__ __forceinline__ unsigned block_scan_incl(unsigned v, unsigned* wt) {
    const int lane = threadIdx.x & 63;
    const int w = threadIdx.x >> 6;
    for (int d = 1; d < 64; d <<= 1) {
        unsigned o = __shfl_up(v, d, 64);
        if (lane >= d) v += o;
    }
    if (lane == 63) wt[w] = v;
    __syncthreads();
    unsigned add = 0;
    for (int i = 0; i < w; ++i) add += wt[i];
    __syncthreads();
    return v + add;
}

__device__ __forceinline__ unsigned block_min(unsigned v, unsigned* wt) {
    for (int d = 32; d >= 1; d >>= 1)
        v = min(v, (unsigned)__shfl_xor((int)v, d, 64));
    if ((threadIdx.x & 63) == 0) wt[threadIdx.x >> 6] = v;
    __syncthreads();
    unsigned r = min(min(wt[0], wt[1]), min(wt[2], wt[3]));
    __syncthreads();
    return r;
}

// Find bin holding the rank-th element in direction order over hist.
// Writes s_b[0]=bin, s_b[1]=rank-within-bin (1-based). All threads call.
template <int NB, int SPAN>
__device__ void locate(const unsigned* hist, unsigned rank, bool fromTop,
                       unsigned* wt, unsigned* s_b) {
    const int t = threadIdx.x;
    const int base = t * SPAN;
    unsigned g = 0;
#pragma unroll
    for (int i = 0; i < SPAN; ++i) {
        int b = fromTop ? (NB - 1 - (base + i)) : (base + i);
        g += hist[b];
    }
    unsigned S = block_scan_incl(g, wt);
    if (S >= rank && (S - g) < rank) {
        unsigned lr = rank - (S - g);
        unsigned acc = 0;
        for (int i = 0; i < SPAN; ++i) {
            int b = fromTop ? (NB - 1 - (base + i)) : (base + i);
            unsigned h = hist[b];
            acc += h;
            if (acc >= lr) { s_b[0] = (unsigned)b; s_b[1] = lr - (acc - h); break; }
        }
    }
    __syncthreads();
}

// rank-th element in direction order (ties by ascending index).
// Returns exact 31-bit key and the element's spatial index e.
__device__ void select_stable(const unsigned* s_x, const unsigned* hist0,
                              unsigned* hist1, unsigned* cand,
                              unsigned* wt, unsigned* s_b,
                              unsigned rank, bool fromTop,
                              unsigned& keyOut, unsigned& eOut) {
    const int t = threadIdx.x;
    locate<NB0, SP0>(hist0, rank, fromTop, wt, s_b);
    unsigned b0 = s_b[0];
    unsigned m  = s_b[1];
    if (t == 0) s_b[3] = 0;
    __syncthreads();
    // compact candidate bin: (low20 << 12) | idx  (order irrelevant)
    for (int j = t; j < HW; j += NT) {
        unsigned key = s_x[j] & 0x7fffffffu;
        if ((key >> 20) == b0) {
            unsigned pos = atomicAdd(&s_b[3], 1u);
            if (pos < CAP) cand[pos] = ((key & 0xFFFFFu) << 12) | (unsigned)j;
        }
    }
    __syncthreads();
    const unsigned cnt = s_b[3];

    if (cnt <= CAP) {
        // pass 1: bits 19..10 of low20
        for (int i = t; i < NB1; i += NT) hist1[i] = 0;
        __syncthreads();
        for (int i = t; i < (int)cnt; i += NT)
            atomicAdd(&hist1[(cand[i] >> 22) & 0x3FFu], 1u);
        __syncthreads();
        locate<NB1, SP1>(hist1, m, fromTop, wt, s_b);
        unsigned d1 = s_b[0]; m = s_b[1];
        // pass 2: bits 9..0, filtered by d1
        for (int i = t; i < NB1; i += NT) hist1[i] = 0;
        __syncthreads();
        for (int i = t; i < (int)cnt; i += NT) {
            unsigned c = cand[i];
            if (((c >> 22) & 0x3FFu) == d1) atomicAdd(&hist1[(c >> 12) & 0x3FFu], 1u);
        }
        __syncthreads();
        locate<NB1, SP1>(hist1, m, fromTop, wt, s_b);
        unsigned d2 = s_b[0]; m = s_b[1];
        __syncthreads();
        const unsigned L = (d1 << 10) | d2;
        // m-th smallest index among candidates with low20 == L (m almost always 1)
        unsigned lb = 0, e = 0;
        for (unsigned it = 0; it < m; ++it) {
            unsigned local = 0xFFFFFFFFu;
            for (int i = t; i < (int)cnt; i += NT) {
                unsigned c = cand[i];
                if ((c >> 12) == L) {
                    unsigned idx = c & 0xFFFu;
                    if (idx >= lb) local = min(local, idx);
                }
            }
            e = block_min(local, wt);
            lb = e + 1;
        }
        keyOut = (b0 << 20) | L;
        eOut = e;
    } else {
        // fallback (pathological distributions): full-row refinement
        for (int i = t; i < NB1; i += NT) hist1[i] = 0;
        __syncthreads();
        for (int j = t; j < HW; j += NT) {
            unsigned key = s_x[j] & 0x7fffffffu;
            if ((key >> 20) == b0) atomicAdd(&hist1[(key >> 10) & 0x3FFu], 1u);
        }
        __syncthreads();
        locate<NB1, SP1>(hist1, m, fromTop, wt, s_b);
        unsigned d1 = s_b[0]; m = s_b[1];
        for (int i = t; i < NB1; i += NT) hist1[i] = 0;
        __syncthreads();
        const unsigned pfx = (b0 << 10) | d1;
        for (int j = t; j < HW; j += NT) {
            unsigned key = s_x[j] & 0x7fffffffu;
            if ((key >> 10) == pfx) atomicAdd(&hist1[key & 0x3FFu], 1u);
        }
        __syncthreads();
        locate<NB1, SP1>(hist1, m, fromTop, wt, s_b);
        unsigned d2 = s_b[0]; m = s_b[1];
        __syncthreads();
        const unsigned K = (pfx << 10) | d2;
        unsigned lb = 0, e = 0;
        for (unsigned it = 0; it < m; ++it) {
            unsigned local = 0xFFFFFFFFu;
            for (int j = t; j < HW; j += NT) {
                unsigned key = s_x[j] & 0x7fffffffu;
                if (key == K && (unsigned)j >= lb) local = min(local, (unsigned)j);
            }
            e = block_min(local, wt);
            lb = e + 1;
        }
        keyOut = K;
        eOut = e;
    }
}

extern "C" __global__ void __launch_bounds__(NT)
topk_kernel(const float* __restrict__ x, float* __restrict__ out) {
    __shared__ uint4 s_x4[HW / 4];        // 12544 B
    __shared__ unsigned s_hist0[NB0];     //  8192 B
    __shared__ unsigned s_hist1[NB1];     //  4096 B
    __shared__ unsigned s_cand[CAP];      //  2048 B
    __shared__ unsigned s_wt[4];
    __shared__ unsigned s_b[4];
    unsigned* s_x = (unsigned*)s_x4;

    const int t = threadIdx.x;
    const int row = blockIdx.x;
    const uint4* __restrict__ xin = (const uint4*)(x + (size_t)row * HW);
    uint4* __restrict__ xout = (uint4*)(out + (size_t)row * HW);

    for (int i = t; i < NB0; i += NT) s_hist0[i] = 0;
    __syncthreads();
    // fused load + level-0 histogram
    for (int j = t; j < HW / 4; j += NT) {
        uint4 v = xin[j];
        s_x4[j] = v;
        atomicAdd(&s_hist0[(v.x & 0x7fffffffu) >> 20], 1u);
        atomicAdd(&s_hist0[(v.y & 0x7fffffffu) >> 20], 1u);
        atomicAdd(&s_hist0[(v.z & 0x7fffffffu) >> 20], 1u);
        atomicAdd(&s_hist0[(v.w & 0x7fffffffu) >> 20], 1u);
    }
    __syncthreads();

    // Select A: k-th largest -> its spatial index tIdx
    unsigned KA, tIdx;
    select_stable(s_x, s_hist0, s_hist1, s_cand, s_wt, s_b, KSEL, true, KA, tIdx);

    if (tIdx == 0) {  // keep nothing
        uint4 z = make_uint4(0u, 0u, 0u, 0u);
        for (int j = t; j < HW / 4; j += NT) xout[j] = z;
        return;
    }

    // Select B: tIdx-th smallest (stable) -> threshold key KB, cutoff index eB
    unsigned KB, eB;
    select_stable(s_x, s_hist0, s_hist1, s_cand, s_wt, s_b, tIdx, false, KB, eB);

    // keep = key < KB  ||  (key == KB && idx <= eB)
    for (int j = t; j < HW / 4; j += NT) {
        uint4 v = s_x4[j];
        const unsigned i0 = 4u * (unsigned)j;
        unsigned k;
        k = v.x & 0x7fffffffu; if (!(k < KB || (k == KB && i0      <= eB))) v.x = 0u;
        k = v.y & 0x7fffffffu; if (!(k < KB || (k == KB && i0 + 1u <= eB))) v.y = 0u;
        k = v.z & 0x7fffffffu; if (!(k < KB || (k == KB && i0 + 2u <= eB))) v.z = 0u;
        k = v.w & 0x7fffffffu; if (!(k < KB || (k == KB && i0 + 3u <= eB))) v.w = 0u;
        xout[j] = v;
    }
}

extern "C" void kernel_launch(void* const* d_in, const int* in_sizes, int n_in,
                              void* d_out, int out_size, void* d_ws, size_t ws_size,
                              hipStream_t stream) {
    const float* x = (const float*)d_in[0];
    float* out = (float*)d_out;
    const int rows = in_sizes[0] / HW;  // 8192
    topk_kernel<<<dim3(rows), dim3(NT), 0, stream>>>(x, out);
}

// Round 3
// 71.587 us; speedup vs baseline: 1.9896x; 1.4811x over previous
//
#include <hip/hip_runtime.h>
#include <stdint.h>

// TopKLayer quirky sparse_hw: per row (3136 elems), t = spatial index of the
// k-th largest |x| (k=313, ties by ascending index); keep the t smallest-|x|
// elements (stable). One block per row. 2048-bin histogram locates the
// candidate bin; exact stable rank resolved by counting over the compacted
// candidates (LDS broadcast reads, one barrier).

#define HW   3136
#define NT   256
#define KSEL 313u
#define NB0  2048        // top 11 bits of 31-bit abs key
#define SP0  (NB0 / NT)  // 8
#define CAP  512         // candidate capacity (stat max ~190 for N(0,1) rows)

__device__ __forceinline__ unsigned block_scan_incl(unsigned v, unsigned* wt) {
    const int lane = threadIdx.x & 63;
    const int w = threadIdx.x >> 6;
    for (int d = 1; d < 64; d <<= 1) {
        unsigned o = __shfl_up(v, d, 64);
        if (lane >= d) v += o;
    }
    if (lane == 63) wt[w] = v;
    __syncthreads();
    unsigned add = 0;
    for (int i = 0; i < w; ++i) add += wt[i];
    __syncthreads();
    return v + add;
}

// Locate bin containing the rank-th element (direction order) in hist0.
// Writes s_b[0]=bin, s_b[1]=rank-within-bin (1-based); zeroes s_b[3].
template <bool fromTop>
__device__ void locate0(const unsigned* hist, unsigned rank,
                        unsigned* wt, unsigned* s_b) {
    const int t = threadIdx.x;
    const int base = t * SP0;
    unsigned g = 0;
#pragma unroll
    for (int i = 0; i < SP0; ++i) {
        int b = fromTop ? (NB0 - 1 - (base + i)) : (base + i);
        g += hist[b];
    }
    unsigned S = block_scan_incl(g, wt);
    if (S >= rank && (S - g) < rank) {
        unsigned lr = rank - (S - g);
        unsigned acc = 0;
        for (int i = 0; i < SP0; ++i) {
            int b = fromTop ? (NB0 - 1 - (base + i)) : (base + i);
            unsigned h = hist[b];
            acc += h;
            if (acc >= lr) { s_b[0] = (unsigned)b; s_b[1] = lr - (acc - h); break; }
        }
    }
    if (t == 0) s_b[3] = 0;
    __syncthreads();
}

// rank-th element in direction order (ties by ascending index).
// Returns exact 31-bit key and the element's spatial index.
template <bool fromTop>
__device__ void select_stable(const uint4* s_x4, const unsigned* hist0,
                              unsigned* cand, unsigned* wt, unsigned* s_b,
                              unsigned rank, unsigned& keyOut, unsigned& eOut) {
    const int t = threadIdx.x;
    locate0<fromTop>(hist0, rank, wt, s_b);
    const unsigned b0 = s_b[0];
    const unsigned m  = s_b[1];

    // compact candidate bin: (low20 << 12) | idx  (order irrelevant)
    for (int j = t; j < HW / 4; j += NT) {
        uint4 v = s_x4[j];
        const unsigned i0 = 4u * (unsigned)j;
        unsigned k;
        k = v.x & 0x7fffffffu;
        if ((k >> 20) == b0) { unsigned p = atomicAdd(&s_b[3], 1u); if (p < CAP) cand[p] = ((k & 0xFFFFFu) << 12) | i0; }
        k = v.y & 0x7fffffffu;
        if ((k >> 20) == b0) { unsigned p = atomicAdd(&s_b[3], 1u); if (p < CAP) cand[p] = ((k & 0xFFFFFu) << 12) | (i0 + 1u); }
        k = v.z & 0x7fffffffu;
        if ((k >> 20) == b0) { unsigned p = atomicAdd(&s_b[3], 1u); if (p < CAP) cand[p] = ((k & 0xFFFFFu) << 12) | (i0 + 2u); }
        k = v.w & 0x7fffffffu;
        if ((k >> 20) == b0) { unsigned p = atomicAdd(&s_b[3], 1u); if (p < CAP) cand[p] = ((k & 0xFFFFFu) << 12) | (i0 + 3u); }
    }
    __syncthreads();
    const unsigned cnt = s_b[3];

    if (cnt <= CAP) {
        // exact stable rank by counting; cand[j] broadcast-read by all threads
        for (int i = t; i < (int)cnt; i += NT) {
            const unsigned ci = cand[i];
            const unsigned Ci = fromTop ? (ci ^ 0xFFFu) : ci;
            unsigned r = 1;
            for (int j = 0; j < (int)cnt; ++j) {
                const unsigned Cj = fromTop ? (cand[j] ^ 0xFFFu) : cand[j];
                if (fromTop ? (Cj > Ci) : (Cj < Ci)) r++;
            }
            if (r == m) s_b[2] = ci;
        }
        __syncthreads();
        const unsigned ci = s_b[2];
        keyOut = (b0 << 20) | (ci >> 12);
        eOut = ci & 0xFFFu;
    } else {
        // pathological fallback: counting rank over the full row, bin-filtered
        const unsigned* s_x = (const unsigned*)s_x4;
        for (int j = t; j < HW; j += NT) {
            const unsigned k = s_x[j] & 0x7fffffffu;
            if ((k >> 20) != b0) continue;
            unsigned Ci = ((k & 0xFFFFFu) << 12) | (unsigned)j;
            if (fromTop) Ci ^= 0xFFFu;
            unsigned r = 1;
            for (int j2 = 0; j2 < HW; ++j2) {
                const unsigned k2 = s_x[j2] & 0x7fffffffu;
                if ((k2 >> 20) != b0) continue;
                unsigned Cj = ((k2 & 0xFFFFFu) << 12) | (unsigned)j2;
                if (fromTop) Cj ^= 0xFFFu;
                if (fromTop ? (Cj > Ci) : (Cj < Ci)) r++;
            }
            if (r == m) s_b[2] = ((k & 0xFFFFFu) << 12) | (unsigned)j;
        }
        __syncthreads();
        const unsigned ci = s_b[2];
        keyOut = (b0 << 20) | (ci >> 12);
        eOut = ci & 0xFFFu;
    }
}

extern "C" __global__ void __launch_bounds__(NT)
topk_kernel(const float* __restrict__ x, float* __restrict__ out) {
    __shared__ uint4 s_x4[HW / 4];        // 12544 B
    __shared__ unsigned s_hist0[NB0];     //  8192 B
    __shared__ unsigned s_cand[CAP];      //  2048 B
    __shared__ unsigned s_wt[4];
    __shared__ unsigned s_b[4];

    const int t = threadIdx.x;
    const int row = blockIdx.x;
    const uint4* __restrict__ xin = (const uint4*)(x + (size_t)row * HW);
    uint4* __restrict__ xout = (uint4*)(out + (size_t)row * HW);

    for (int i = t; i < NB0; i += NT) s_hist0[i] = 0;
    __syncthreads();
    // fused load + level-0 histogram
    for (int j = t; j < HW / 4; j += NT) {
        uint4 v = xin[j];
        s_x4[j] = v;
        atomicAdd(&s_hist0[(v.x & 0x7fffffffu) >> 20], 1u);
        atomicAdd(&s_hist0[(v.y & 0x7fffffffu) >> 20], 1u);
        atomicAdd(&s_hist0[(v.z & 0x7fffffffu) >> 20], 1u);
        atomicAdd(&s_hist0[(v.w & 0x7fffffffu) >> 20], 1u);
    }
    __syncthreads();

    // Select A: k-th largest -> its spatial index tIdx
    unsigned KA, tIdx;
    select_stable<true>(s_x4, s_hist0, s_cand, s_wt, s_b, KSEL, KA, tIdx);

    if (tIdx == 0) {  // keep nothing
        uint4 z = make_uint4(0u, 0u, 0u, 0u);
        for (int j = t; j < HW / 4; j += NT) xout[j] = z;
        return;
    }

    // Select B: tIdx-th smallest (stable) -> threshold key KB, cutoff index eB
    unsigned KB, eB;
    select_stable<false>(s_x4, s_hist0, s_cand, s_wt, s_b, tIdx, KB, eB);

    // keep = key < KB  ||  (key == KB && idx <= eB)
    for (int j = t; j < HW / 4; j += NT) {
        uint4 v = s_x4[j];
        const unsigned i0 = 4u * (unsigned)j;
        unsigned k;
        k = v.x & 0x7fffffffu; if (!(k < KB || (k == KB && i0      <= eB))) v.x = 0u;
        k = v.y & 0x7fffffffu; if (!(k < KB || (k == KB && i0 + 1u <= eB))) v.y = 0u;
        k = v.z & 0x7fffffffu; if (!(k < KB || (k == KB && i0 + 2u <= eB))) v.z = 0u;
        k = v.w & 0x7fffffffu; if (!(k < KB || (k == KB && i0 + 3u <= eB))) v.w = 0u;
        xout[j] = v;
    }
}

extern "C" void kernel_launch(void* const* d_in, const int* in_sizes, int n_in,
                              void* d_out, int out_size, void* d_ws, size_t ws_size,
                              hipStream_t stream) {
    const float* x = (const float*)d_in[0];
    float* out = (float*)d_out;
    const int rows = in_sizes[0] / HW;  // 8192
    topk_kernel<<<dim3(rows), dim3(NT), 0, stream>>>(x, out);
}